// Round 4
// baseline (149.036 us; speedup 1.0000x reference)
//
#include <hip/hip_runtime.h>
#include <math.h>

// Problem constants (reference: B,F,W,H,D = 128,1024,32,64,64)
#define B_   128
#define F_   1024
#define W_   32
#define H_   64
#define K4H  256          // 4*H
#define K2_  (2 * F_)     // 2048: fp32 split into interleaved (hi,lo) bf16 pairs
#define KU_  (K2_ / 2)    // 1024 packed uints per row (A2 per-t row, B2 per-n row)

typedef __attribute__((ext_vector_type(8))) short  short8;  // 8 bf16 (MFMA A/B frag)
typedef __attribute__((ext_vector_type(4))) float  f32x4;   // MFMA C/D frag

// ---------------------------------------------------------------------------
// fp32 -> (hi,lo) bf16 pair packed into one uint: short[0]=hi (k2 even),
// short[1]=lo (k2 odd). hi=RNE(v), lo=RNE(v-hi) -> fp32 product via plain
// bf16 MFMA over doubled K, near-exact.
// ---------------------------------------------------------------------------
__device__ __forceinline__ unsigned bf16_rne(float v) {
  unsigned u = __float_as_uint(v);
  return (u + 0x7FFFu + ((u >> 16) & 1u)) >> 16;
}
__device__ __forceinline__ unsigned pack_hilo(float v) {
  unsigned hi = bf16_rne(v);
  float    hf = __uint_as_float(hi << 16);
  unsigned lo = bf16_rne(v - hf);
  return hi | (lo << 16);
}
__device__ __forceinline__ short8 as_s8(uint4 v) {
  union { uint4 u; short8 s; } x; x.u = v; return x.s;
}

// ---------------------------------------------------------------------------
// prep: one kernel, two block roles.
//  blocks [0,64):    Wx [F,4H] -> B2 [4H][KU_], transposed, hi/lo packed,
//                    GRANULE-PERMUTED (within each 32-uint K-tile, granule
//                    (s*4+q) stored at (q*2+s)) so a lane's two MFMA B-frags
//                    are adjacent uint4s. (identical to R2's conv_w)
//  blocks [64,4160): x [B,F,W] -> A2 [B][W][KU_]: A2[b][t][f]=pack(x[b][f][t]).
//                    This moves the A transpose+pack OUT of the recurrence
//                    kernel, letting phase 1 run with no LDS and no barriers.
// ---------------------------------------------------------------------------
__global__ __launch_bounds__(256) void prep(const float* __restrict__ Wx,
                                            const float* __restrict__ x,
                                            unsigned* __restrict__ B2,
                                            unsigned* __restrict__ A2) {
  __shared__ unsigned lds[256 * 17];   // conv role: [256][17]; pack role: [32][36]
  const int tid = threadIdx.x;
  if ((int)blockIdx.x < 64) {          // ---- Wx -> B2 ----
    const int f0 = blockIdx.x * 16;
#pragma unroll
    for (int i = 0; i < 4; ++i) {
      int l = tid + i * 256;           // 1024 float4 slots = 16 f x 64 n-groups
      int n0 = (l & 63) * 4;
      int fl = l >> 6;                 // 0..15
      float4 v = *(const float4*)&Wx[(size_t)(f0 + fl) * K4H + n0];
      lds[(n0 + 0) * 17 + fl] = pack_hilo(v.x);
      lds[(n0 + 1) * 17 + fl] = pack_hilo(v.y);
      lds[(n0 + 2) * 17 + fl] = pack_hilo(v.z);
      lds[(n0 + 3) * 17 + fl] = pack_hilo(v.w);
    }
    __syncthreads();
    const int tb = f0 & ~31;           // 32-uint K-tile base
    const int s  = (f0 >> 4) & 1;      // which MFMA k-step this 16-f chunk is
#pragma unroll
    for (int i = 0; i < 4; ++i) {
      int l  = tid + i * 256;          // 1024 uint4 slots = 256 n x 4 granules
      int qg = l & 3;
      int n  = l >> 2;
      uint4 o;
      o.x = lds[n * 17 + qg * 4 + 0];
      o.y = lds[n * 17 + qg * 4 + 1];
      o.z = lds[n * 17 + qg * 4 + 2];
      o.w = lds[n * 17 + qg * 4 + 3];
      *(uint4*)&B2[(size_t)n * KU_ + tb + qg * 8 + s * 4] = o;
    }
  } else {                             // ---- x -> A2 (transpose + pack) ----
    const int bid = blockIdx.x - 64;
    const int b   = bid >> 5;          // 0..127
    const int f0  = (bid & 31) * 32;   // 32-f chunk
    const int t0  = (tid & 7) * 4;
    const int fl  = tid >> 3;          // 0..31
    float4 v = *(const float4*)&x[((size_t)b * F_ + (f0 + fl)) * W_ + t0];
    float vals[4] = {v.x, v.y, v.z, v.w};
#pragma unroll
    for (int j = 0; j < 4; ++j)
      lds[(t0 + j) * 36 + fl] = pack_hilo(vals[j]);
    __syncthreads();
    const int t = tid >> 3, fg = tid & 7;
    uint4 o = *(const uint4*)&lds[t * 36 + fg * 4];
    *(uint4*)&A2[((size_t)b * W_ + t) * KU_ + f0 + fg * 4] = o;
  }
}

// ---------------------------------------------------------------------------
__device__ __forceinline__ float bcastlane(float v, int l) {
  return __uint_as_float(__builtin_amdgcn_readlane(__float_as_uint(v), l));
}
__device__ __forceinline__ float sigm(float v)   { return 1.f / (1.f + __expf(-v)); }
__device__ __forceinline__ float tanh_f(float v) { return 1.f - 2.f / (__expf(2.f * v) + 1.f); }

// ---------------------------------------------------------------------------
// Fused per-batch kernel, R3/R4: phase 1 is BARRIER-FREE and LDS-FREE.
// A and B fragments both come global->VGPR in exact MFMA layout (prepacked
// A2/B2), double-buffered two stages deep -> per-wave in-order pipelining
// with counted vmcnt waits; no __syncthreads drains in the GEMM at all
// (R2's per-stage full vmcnt(0) drain at 1 wave/SIMD was the stall).
// Phase 2: per-step barrier drains LDS only -- the c-output is stashed in
// the dead sG row and copied to global once, coalesced, at the end.
// ---------------------------------------------------------------------------
__global__ __launch_bounds__(256, 1) void fused_rnn(
    const unsigned* __restrict__ A2,  // [B][W][KU_] packed
    const unsigned* __restrict__ B2,  // [4H][KU_] packed+permuted
    const float* __restrict__ Wh,     // [H, 4H]
    const float* __restrict__ bl,     // [4H]
    float* __restrict__ out) {        // [B, W, H]
  __shared__ float sG[32][260];       // gate pre-activations, +4 pad
  __shared__ float sact[2][4][64];    // [t-parity][gate-wave][u]

  const int tid  = threadIdx.x;
  const int b    = blockIdx.x;               // one block per batch element
  const int wv   = tid >> 6, lane = tid & 63;
  const int lm   = lane & 15, q = lane >> 4; // MFMA lane decomposition

  f32x4 acc[2][4];                           // 32 t x 64 n per wave
#pragma unroll
  for (int a = 0; a < 2; ++a)
#pragma unroll
    for (int bb = 0; bb < 4; ++bb) acc[a][bb] = (f32x4){0.f, 0.f, 0.f, 0.f};

  // Fragment base pointers. A frag (mt,st): row mt*16+lm, uints it*32+st*16+q*4.
  // B frag (nt,st): row wv*64+nt*16+lm, uints it*32 + q*8 + st*4 (permuted).
  const unsigned* Ar0 = &A2[((size_t)b * W_ + lm) * KU_ + q * 4];
  const unsigned* Ar1 = Ar0 + (size_t)16 * KU_;
  const unsigned* Br  = &B2[(size_t)(wv * 64 + lm) * KU_ + q * 8];

  uint4 a0[4], b0[8], a1[4], b1[8];
  auto loadA = [&](int it, uint4* d) {
    d[0] = *(const uint4*)(Ar0 + it * 32);
    d[1] = *(const uint4*)(Ar0 + it * 32 + 16);
    d[2] = *(const uint4*)(Ar1 + it * 32);
    d[3] = *(const uint4*)(Ar1 + it * 32 + 16);
  };
  auto loadB = [&](int it, uint4* d) {
#pragma unroll
    for (int nt = 0; nt < 4; ++nt) {
      const unsigned* p = Br + (size_t)nt * 16 * KU_ + it * 32;
      d[nt * 2 + 0] = *(const uint4*)p;        // step-0 frag
      d[nt * 2 + 1] = *(const uint4*)(p + 4);  // step-1 frag
    }
  };
  auto domfma = [&](uint4* a, uint4* bb) {
#pragma unroll
    for (int st = 0; st < 2; ++st)
#pragma unroll
      for (int mt = 0; mt < 2; ++mt)
#pragma unroll
        for (int nt = 0; nt < 4; ++nt)
          acc[mt][nt] = __builtin_amdgcn_mfma_f32_16x16x32_bf16(
              as_s8(a[mt * 2 + st]), as_s8(bb[nt * 2 + st]), acc[mt][nt], 0, 0, 0);
  };

  // 2-stage-deep software pipeline; all reg indices compile-time constant.
  loadA(0, a0); loadB(0, b0);
  loadA(1, a1); loadB(1, b1);
#pragma unroll 1
  for (int it = 0; it < 32; it += 2) {
    domfma(a0, b0);                            // waits (counted) on a0/b0
    if (it + 2 < 32) { loadA(it + 2, a0); loadB(it + 2, b0); }
    domfma(a1, b1);
    if (it + 3 < 32) { loadA(it + 3, a1); loadB(it + 3, b1); }
  }

  // Phase 2 setup: issue Wh column loads NOW so their latency hides under
  // the sG exchange + barrier. Thread (wv,lane) owns gate col k.
  const int k = wv * 64 + lane;
  float wc[64];                              // Wh column k, register-resident
#pragma unroll
  for (int j = 0; j < 64; ++j) wc[j] = Wh[j * K4H + k];
  const float bk = bl[k];

  // Accumulators -> LDS. C/D layout col=lane&15, row=q*4+reg [m89-verified].
#pragma unroll
  for (int mt = 0; mt < 2; ++mt)
#pragma unroll
    for (int nt = 0; nt < 4; ++nt)
#pragma unroll
      for (int r = 0; r < 4; ++r)
        sG[mt * 16 + q * 4 + r][wv * 64 + nt * 16 + lm] = acc[mt][nt][r];
  __syncthreads();

  // Sequential LSTM: wave 0/1/2/3 = i/f/g/o gates (tanh branch wave-uniform).
  // h replicated per wave; dot via readlane broadcast, 4 split FMA chains;
  // one barrier/step. No global ops inside the loop: c goes into the dead
  // sG row (row t is never read after step t), so the per-step barrier
  // drains only LDS (lgkm), not vmcnt.
  float h = 0.f, c = 0.f;
  float gc = sG[0][k];
#pragma unroll 1
  for (int t = 0; t < W_; ++t) {
    float gn = (t + 1 < W_) ? sG[t + 1][k] : 0.f;  // hide LDS latency
    float g0 = gc + bk, g1 = 0.f, g2 = 0.f, g3 = 0.f;
#pragma unroll
    for (int j = 0; j < 64; j += 4) {        // 4 independent FMA chains
      g0 = fmaf(bcastlane(h, j),     wc[j],     g0);
      g1 = fmaf(bcastlane(h, j + 1), wc[j + 1], g1);
      g2 = fmaf(bcastlane(h, j + 2), wc[j + 2], g2);
      g3 = fmaf(bcastlane(h, j + 3), wc[j + 3], g3);
    }
    float g = (g0 + g1) + (g2 + g3);
    float act = (wv == 2) ? tanh_f(g) : sigm(g);  // wave-uniform branch
    sact[t & 1][wv][lane] = act;
    __syncthreads();                         // the single barrier per step
    float si = sact[t & 1][0][lane];
    float sf = sact[t & 1][1][lane];
    float tg = sact[t & 1][2][lane];
    float so = sact[t & 1][3][lane];
    c = fmaf(sf, c, si * tg);                // replicated in all 4 waves
    h = so * tanh_f(c);
    if (wv == 0) sG[t][lane] = c;            // stash cell state in dead row
    gc = gn;
  }
  __syncthreads();

  // Coalesced epilogue: sG[t][0..63] -> out[b][t][:], 512 float4 total.
#pragma unroll
  for (int i = 0; i < 2; ++i) {
    int id = tid * 2 + i;
    int t  = id >> 4, u4 = (id & 15) * 4;
    float4 o = *(const float4*)&sG[t][u4];
    *(float4*)&out[((size_t)b * W_ + t) * H_ + u4] = o;
  }
}

// ---------------------------------------------------------------------------
extern "C" void kernel_launch(void* const* d_in, const int* in_sizes, int n_in,
                              void* d_out, int out_size, void* d_ws, size_t ws_size,
                              hipStream_t stream) {
  // 0:x 1:W_state 2:b_state 3:W_in 4:w_attn 5:b_attn 6:Wx 7:Wh 8:b_lstm
  const float* x      = (const float*)d_in[0];
  const float* Wx     = (const float*)d_in[6];
  const float* Wh     = (const float*)d_in[7];
  const float* b_lstm = (const float*)d_in[8];
  float* out = (float*)d_out;

  // Workspace: B2 (1 MB) then A2 (16 MB). Harness provides >=256 MB.
  unsigned* B2 = (unsigned*)d_ws;
  unsigned* A2 = B2 + (1u << 18);   // +1 MB in uints

  prep     <<<dim3(64 + B_ * 32), dim3(256), 0, stream>>>(Wx, x, B2, A2);
  fused_rnn<<<dim3(B_),           dim3(256), 0, stream>>>(A2, B2, Wh, b_lstm, out);
}

// Round 6
// 124.611 us; speedup vs baseline: 1.1960x; 1.1960x over previous
//
#include <hip/hip_runtime.h>
#include <math.h>

// Problem constants (reference: B,F,W,H,D = 128,1024,32,64,64)
#define B_   128
#define F_   1024
#define W_   32
#define H_   64
#define K4H  256          // 4*H
#define M_   (B_ * W_)    // 4096 rows of the gate GEMM (m = b*32 + t)
#define K2_  (2 * F_)     // 2048: fp32 split into interleaved (hi,lo) bf16 pairs

typedef __attribute__((ext_vector_type(8))) short  short8;  // 8 bf16 (MFMA A/B frag)
typedef __attribute__((ext_vector_type(4))) float  f32x4;   // MFMA C/D frag

// ---------------------------------------------------------------------------
// fp32 -> (hi,lo) bf16 pair packed into one uint: short[0]=hi (k2 even),
// short[1]=lo (k2 odd). hi=RNE(v), lo=RNE(v-hi) -> fp32 product via plain
// bf16 MFMA over doubled K, near-exact.
// ---------------------------------------------------------------------------
__device__ __forceinline__ unsigned bf16_rne(float v) {
  unsigned u = __float_as_uint(v);
  return (u + 0x7FFFu + ((u >> 16) & 1u)) >> 16;
}
__device__ __forceinline__ unsigned pack_hilo(float v) {
  unsigned hi = bf16_rne(v);
  float    hf = __uint_as_float(hi << 16);
  unsigned lo = bf16_rne(v - hf);
  return hi | (lo << 16);
}

// ---------------------------------------------------------------------------
// Wx [F,4H] fp32 -> B2 [4H][K2/2] uints (transposed, hi/lo packed).
// (R0-verified verbatim.)
// ---------------------------------------------------------------------------
__global__ __launch_bounds__(256) void conv_w(const float* __restrict__ Wx,
                                              unsigned* __restrict__ B2) {
  __shared__ unsigned T[256][17];  // [n][f_local], +1 pad
  const int tid = threadIdx.x;
  const int f0  = blockIdx.x * 16;
#pragma unroll
  for (int i = 0; i < 4; ++i) {
    int l = tid + i * 256;          // 1024 float4 slots = 16 f x 64 n-groups
    int n0 = (l & 63) * 4;
    int fl = l >> 6;                // 0..15
    float4 v = *(const float4*)&Wx[(size_t)(f0 + fl) * K4H + n0];
    T[n0 + 0][fl] = pack_hilo(v.x);
    T[n0 + 1][fl] = pack_hilo(v.y);
    T[n0 + 2][fl] = pack_hilo(v.z);
    T[n0 + 3][fl] = pack_hilo(v.w);
  }
  __syncthreads();
#pragma unroll
  for (int i = 0; i < 4; ++i) {
    int l  = tid + i * 256;         // 1024 uint4 slots = 256 n x 4
    int c4 = (l & 3) * 4;
    int n  = l >> 2;
    uint4 o;
    o.x = T[n][c4 + 0]; o.y = T[n][c4 + 1]; o.z = T[n][c4 + 2]; o.w = T[n][c4 + 3];
    *(uint4*)&B2[(size_t)n * (K2_ / 2) + f0 + c4] = o;
  }
}

// ---------------------------------------------------------------------------
// Gate GEMM via MFMA (R0-verified verbatim; measured fast in the 119.6us
// pipeline). Block tile 128(M)x128(N), 4 waves with 64x64 wave tiles (4x4 of
// 16x16x32 bf16 MFMAs = 32 MFMA/stage), K-split S. Grid (32, 2, S).
// ---------------------------------------------------------------------------
template <int S>
__global__ __launch_bounds__(256, 1) void gemm_mfma(
    const float* __restrict__ x,      // [B, F, W]
    const unsigned* __restrict__ B2,  // [4H][K2/2] packed
    float* __restrict__ Gp) {         // [S][M][4H] partials
  constexpr int NIT = 32 / S;         // stage iters of 32 f (64 k2) each
  __shared__ unsigned lA[128 * 36];
  __shared__ unsigned lB[128 * 36];
  const int tid   = threadIdx.x;
  const int mtile = blockIdx.x;       // 0..31 (4 batches per tile)
  const int ntile = blockIdx.y;       // 0..1  (128 gate cols)
  const int s     = blockIdx.z;       // 0..S-1
  const int wv = tid >> 6, lane = tid & 63;
  const int wm = wv & 1, wn = wv >> 1;      // wave -> 64x64 quadrant
  const int lm = lane & 15, q = lane >> 4;  // MFMA lane decomposition

  f32x4 acc[4][4];
#pragma unroll
  for (int a = 0; a < 4; ++a)
#pragma unroll
    for (int bb = 0; bb < 4; ++bb) acc[a][bb] = (f32x4){0.f, 0.f, 0.f, 0.f};

  const int b0 = mtile * 4;
  float4 ax[4];
  uint4  bxr[4];

  auto prefetch = [&](int iter) {
    const int f0 = (s * NIT + iter) * 32;
#pragma unroll
    for (int i = 0; i < 4; ++i) {
      int l  = tid + i * 256;       // 1024 float4 = 4 b x 32 f x 8 t-groups
      int t0 = (l & 7) * 4;
      int fl = (l >> 3) & 31;
      int bl = l >> 8;
      ax[i] = *(const float4*)&x[(((size_t)(b0 + bl)) * F_ + (f0 + fl)) * W_ + t0];
    }
#pragma unroll
    for (int i = 0; i < 4; ++i) {
      int l   = tid + i * 256;      // 1024 uint4 = 128 n x 8
      int c16 = l & 7;
      int nl  = l >> 3;
      bxr[i] = *(const uint4*)&B2[(size_t)(ntile * 128 + nl) * (K2_ / 2) + f0 + c16 * 4];
    }
  };

  prefetch(0);
  const int jx = (tid >> 3) & 3;     // XOR bank-spread for A's b32 writes
  for (int iter = 0; iter < NIT; ++iter) {
    __syncthreads();                 // previous iter's frag reads done
#pragma unroll
    for (int i = 0; i < 4; ++i) {    // A: convert + transpose (t -> row m)
      int l  = tid + i * 256;
      int t0 = (l & 7) * 4;
      int fl = (l >> 3) & 31;
      int bl = l >> 8;
      int m0 = bl * 32 + t0;
      float vals[4] = {ax[i].x, ax[i].y, ax[i].z, ax[i].w};
#pragma unroll
      for (int j = 0; j < 4; ++j) {
        int jj = j ^ jx;
        lA[(m0 + jj) * 36 + fl] = pack_hilo(vals[jj]);
      }
    }
#pragma unroll
    for (int i = 0; i < 4; ++i) {    // B: straight b128 copy (pre-packed)
      int l   = tid + i * 256;
      int c16 = l & 7;
      int nl  = l >> 3;
      *(uint4*)&lB[nl * 36 + c16 * 4] = bxr[i];
    }
    __syncthreads();
    if (iter + 1 < NIT) prefetch(iter + 1);  // overlap globals with MFMA
#pragma unroll
    for (int step = 0; step < 2; ++step) {   // 2 x K2=32 MFMA steps
      short8 aF[4], bF[4];
#pragma unroll
      for (int mt = 0; mt < 4; ++mt) {
        int row = wm * 64 + mt * 16 + lm;    // A[m=lane&15][k=q*8+j]
        aF[mt] = *(const short8*)&lA[row * 36 + step * 16 + q * 4];
      }
#pragma unroll
      for (int nt = 0; nt < 4; ++nt) {
        int row = wn * 64 + nt * 16 + lm;    // B[k=q*8+j][n=lane&15]
        bF[nt] = *(const short8*)&lB[row * 36 + step * 16 + q * 4];
      }
#pragma unroll
      for (int mt = 0; mt < 4; ++mt)
#pragma unroll
        for (int nt = 0; nt < 4; ++nt)
          acc[mt][nt] = __builtin_amdgcn_mfma_f32_16x16x32_bf16(
              aF[mt], bF[nt], acc[mt][nt], 0, 0, 0);
    }
  }
  // epilogue: C/D layout col=lane&15, row=q*4+reg  [m89-verified]
  float* Gs = Gp + (size_t)s * ((size_t)M_ * K4H);
#pragma unroll
  for (int mt = 0; mt < 4; ++mt)
#pragma unroll
    for (int nt = 0; nt < 4; ++nt)
#pragma unroll
      for (int r = 0; r < 4; ++r) {
        int m = mtile * 128 + wm * 64 + mt * 16 + q * 4 + r;
        int n = ntile * 128 + wn * 64 + nt * 16 + lm;
        Gs[(size_t)m * K4H + n] = acc[mt][nt][r];
      }
}

// ---------------------------------------------------------------------------
__device__ __forceinline__ float bcastlane(float v, int l) {
  return __uint_as_float(__builtin_amdgcn_readlane(__float_as_uint(v), l));
}
__device__ __forceinline__ float sigm(float v)   { return 1.f / (1.f + __expf(-v)); }
__device__ __forceinline__ float tanh_f(float v) { return 1.f - 2.f / (__expf(2.f * v) + 1.f); }

// ---------------------------------------------------------------------------
// Sequential LSTM, R6 (= R5 with the preload index fix): the ENTIRE
// per-batch gate slab (S partials summed, 32x256 f32 = 32 KB) is preloaded
// into LDS up front with coalesced float4 reads -- the recurrence loop has
// ZERO global memory operations. A gate row is 256 f32 = 64 float4, so the
// 2048 float4 slots decompose as t = idx>>6, c = idx&63 (R5's >>5/&31 wrote
// past sG and skipped the g/o gate columns -> absmax 2.55 fail).
// ---------------------------------------------------------------------------
template <int S>
__global__ __launch_bounds__(256, 1) void lstm_seq(
    const float* __restrict__ Gp, const float* __restrict__ Wh,
    const float* __restrict__ bl, float* __restrict__ out) {
  __shared__ float sG[32 * 260];              // [t][k], +4 pad per row
  __shared__ float sact[2][4][64];            // [t-parity][gate-wave][u]
  const int b = blockIdx.x, tid = threadIdx.x;
  const int w = tid >> 6, u = tid & 63;
  const int k = w * 64 + u;                   // gate column

  // Wh column loads issue first; latency hides under the slab preload.
  float wc[64];                               // Wh column k, register-resident
#pragma unroll
  for (int j = 0; j < 64; ++j) wc[j] = Wh[j * K4H + k];
  const float bk = bl[k];

  // Preload + K-split-sum the batch slab: sum_s Gp[s][b*32+t][:] -> sG[t][:].
  // 2048 float4 = 32 t x 64 float4/row; 8 per thread, coalesced; summation
  // order s=0..S-1 matches R0 exactly (bit-identical results).
  const float4* G4 = (const float4*)Gp + (size_t)b * 32 * (K4H / 4);
  const size_t  s4 = (size_t)M_ * K4H / 4;    // float4 stride between partials
#pragma unroll
  for (int i = 0; i < 8; ++i) {
    int idx = tid + i * 256;                  // 0..2047
    int t = idx >> 6, c = idx & 63;           // 64 float4 per 256-col row
    float4 v = G4[(size_t)t * (K4H / 4) + c];
#pragma unroll
    for (int ss = 1; ss < S; ++ss) {
      float4 p = G4[(size_t)ss * s4 + (size_t)t * (K4H / 4) + c];
      v.x += p.x; v.y += p.y; v.z += p.z; v.w += p.w;
    }
    *(float4*)&sG[t * 260 + c * 4] = v;       // 1040B row stride, 16B aligned
  }
  __syncthreads();

  // Recurrence: wave 0/1/2/3 = i/f/g/o gates (tanh branch wave-uniform).
  // h replicated per wave (lane u = h[u]); dot via readlane broadcast, 4
  // split FMA chains; ONE barrier per step; no vmem in the loop.
  float h = 0.f, c = 0.f;
  float gc = sG[k];
#pragma unroll 1
  for (int t = 0; t < W_; ++t) {
    float gn = (t + 1 < W_) ? sG[(t + 1) * 260 + k] : 0.f;
    float g0 = gc + bk, g1 = 0.f, g2 = 0.f, g3 = 0.f;
#pragma unroll
    for (int j = 0; j < 64; j += 4) {         // 4 independent FMA chains
      g0 = fmaf(bcastlane(h, j),     wc[j],     g0);
      g1 = fmaf(bcastlane(h, j + 1), wc[j + 1], g1);
      g2 = fmaf(bcastlane(h, j + 2), wc[j + 2], g2);
      g3 = fmaf(bcastlane(h, j + 3), wc[j + 3], g3);
    }
    float g = (g0 + g1) + (g2 + g3);
    float act = (w == 2) ? tanh_f(g) : sigm(g);   // wave-uniform branch
    sact[t & 1][w][u] = act;
    __syncthreads();                          // the single barrier per step
    float si = sact[t & 1][0][u];
    float sf = sact[t & 1][1][u];
    float tg = sact[t & 1][2][u];
    float so = sact[t & 1][3][u];
    c = fmaf(sf, c, si * tg);                 // replicated in all 4 waves
    h = so * tanh_f(c);
    if (w == 0) sG[t * 260 + u] = c;          // stash cell state in dead row
    gc = gn;
  }
  __syncthreads();

  // Coalesced epilogue: sG[t][0..63] -> out[b][t][:], 512 float4 total.
#pragma unroll
  for (int i = 0; i < 2; ++i) {
    int id = tid * 2 + i;
    int t  = id >> 4, u4 = (id & 15) * 4;
    float4 o = *(const float4*)&sG[t * 260 + u4];
    *(float4*)&out[((size_t)b * W_ + t) * H_ + u4] = o;
  }
}

// ---------------------------------------------------------------------------
extern "C" void kernel_launch(void* const* d_in, const int* in_sizes, int n_in,
                              void* d_out, int out_size, void* d_ws, size_t ws_size,
                              hipStream_t stream) {
  // 0:x 1:W_state 2:b_state 3:W_in 4:w_attn 5:b_attn 6:Wx 7:Wh 8:b_lstm
  const float* x      = (const float*)d_in[0];
  const float* Wx     = (const float*)d_in[6];
  const float* Wh     = (const float*)d_in[7];
  const float* b_lstm = (const float*)d_in[8];
  float* out = (float*)d_out;

  const size_t gbytes = (size_t)M_ * K4H * sizeof(float);  // 4 MB per partial

  if (ws_size >= 4 * gbytes + (1u << 20)) {     // S = 4: 256 gemm blocks
    float*    Gp = (float*)d_ws;
    unsigned* B2 = (unsigned*)((char*)d_ws + 4 * gbytes);
    conv_w      <<<dim3(64),       dim3(256), 0, stream>>>(Wx, B2);
    gemm_mfma<4><<<dim3(32, 2, 4), dim3(256), 0, stream>>>(x, B2, Gp);
    lstm_seq<4> <<<dim3(B_),       dim3(256), 0, stream>>>(Gp, Wh, b_lstm, out);
  } else if (ws_size >= 2 * gbytes + (1u << 20)) {  // S = 2
    float*    Gp = (float*)d_ws;
    unsigned* B2 = (unsigned*)((char*)d_ws + 2 * gbytes);
    conv_w      <<<dim3(64),       dim3(256), 0, stream>>>(Wx, B2);
    gemm_mfma<2><<<dim3(32, 2, 2), dim3(256), 0, stream>>>(x, B2, Gp);
    lstm_seq<2> <<<dim3(B_),       dim3(256), 0, stream>>>(Gp, Wh, b_lstm, out);
  } else {                                      // S = 1 fallback (5 MB ws)
    float*    Gp = (float*)d_ws;
    unsigned* B2 = (unsigned*)((char*)d_ws + gbytes);
    conv_w      <<<dim3(64),       dim3(256), 0, stream>>>(Wx, B2);
    gemm_mfma<1><<<dim3(32, 2, 1), dim3(256), 0, stream>>>(x, B2, Gp);
    lstm_seq<1> <<<dim3(B_),       dim3(256), 0, stream>>>(Gp, Wh, b_lstm, out);
  }
}